// Round 1
// baseline (1267.731 us; speedup 1.0000x reference)
//
#include <hip/hip_runtime.h>
#include <cmath>

namespace {

constexpr int B  = 256;
constexpr int P  = 361;
constexpr int Fd = 20;
constexpr int H1 = 16;
constexpr int H2 = 32;
constexpr int D  = 32;
constexpr int BP = B * P;   // 92416 = 361 * 256 exactly

__device__ __forceinline__ float gelu_f(float v) {
    // exact gelu: 0.5*v*(1+erf(v/sqrt(2)))
    return 0.5f * v * (1.0f + erff(v * 0.70710678118654752440f));
}

__device__ __forceinline__ void branch_eval(
    float xv,
    const float* __restrict__ W1, const float* __restrict__ b1,
    const float* __restrict__ W2, const float* __restrict__ b2,
    const float* __restrict__ W3, const float* __restrict__ b3,
    float (&outv)[D])
{
    float h1[H1];
#pragma unroll
    for (int i = 0; i < H1; ++i)
        h1[i] = gelu_f(fmaf(xv, W1[i], b1[i]));

    float h2[H2];
#pragma unroll
    for (int o = 0; o < H2; ++o) {
        float s = b2[o];
#pragma unroll
        for (int i = 0; i < H1; ++i)
            s = fmaf(h1[i], W2[i * H2 + o], s);
        h2[o] = gelu_f(s);
    }

#pragma unroll
    for (int o = 0; o < D; ++o) {
        float s = b3[o];
#pragma unroll
        for (int i = 0; i < H2; ++i)
            s = fmaf(h2[i], W3[i * D + o], s);
        outv[o] = s;
    }
}

__global__ __launch_bounds__(256, 2) void dcp_kernel(
    const float* __restrict__ x,
    const float* __restrict__ Wr1, const float* __restrict__ br1,
    const float* __restrict__ Wr2, const float* __restrict__ br2,
    const float* __restrict__ Wr3, const float* __restrict__ br3,
    const float* __restrict__ Wi1, const float* __restrict__ bi1,
    const float* __restrict__ Wi2, const float* __restrict__ bi2,
    const float* __restrict__ Wi3, const float* __restrict__ bi3,
    const float* __restrict__ Wf1, const float* __restrict__ bf1,
    const float* __restrict__ Wf2, const float* __restrict__ bf2,
    float* __restrict__ out)
{
    const int f  = blockIdx.y;                      // wave-uniform -> scalar weight loads
    const int bp = blockIdx.x * blockDim.x + threadIdx.x;

    const float2 xv = *reinterpret_cast<const float2*>(x + ((size_t)bp * Fd + f) * 2);

    float ro[D], io[D];
    branch_eval(xv.x,
                Wr1 + f * H1, br1 + f * H1,
                Wr2 + f * H1 * H2, br2 + f * H2,
                Wr3 + f * H2 * D, br3 + f * D, ro);
    branch_eval(xv.y,
                Wi1 + f * H1, bi1 + f * H1,
                Wi2 + f * H1 * H2, bi2 + f * H2,
                Wi3 + f * H2 * D, bi3 + f * D, io);

    // fused head layer 1: c = [ro, io] (64) -> 32, gelu
    const float* __restrict__ Wf1f = Wf1 + f * (2 * D) * D;
    const float* __restrict__ bf1f = bf1 + f * D;
    float g[D];
#pragma unroll
    for (int o = 0; o < D; ++o) {
        float s = bf1f[o];
#pragma unroll
        for (int i = 0; i < D; ++i)
            s = fmaf(ro[i], Wf1f[i * D + o], s);
#pragma unroll
        for (int i = 0; i < D; ++i)
            s = fmaf(io[i], Wf1f[(D + i) * D + o], s);
        g[o] = gelu_f(s);
    }

    // fused head layer 2: 32 -> 32, gelu
    const float* __restrict__ Wf2f = Wf2 + f * D * D;
    const float* __restrict__ bf2f = bf2 + f * D;
    float res[D];
#pragma unroll
    for (int o = 0; o < D; ++o) {
        float s = bf2f[o];
#pragma unroll
        for (int i = 0; i < D; ++i)
            s = fmaf(g[i], Wf2f[i * D + o], s);
        res[o] = gelu_f(s);
    }

    float4* __restrict__ outp =
        reinterpret_cast<float4*>(out + ((size_t)bp * Fd + f) * D);
#pragma unroll
    for (int j = 0; j < D / 4; ++j)
        outp[j] = make_float4(res[4 * j], res[4 * j + 1], res[4 * j + 2], res[4 * j + 3]);
}

} // anonymous namespace

extern "C" void kernel_launch(void* const* d_in, const int* in_sizes, int n_in,
                              void* d_out, int out_size, void* d_ws, size_t ws_size,
                              hipStream_t stream)
{
    const float* x   = (const float*)d_in[0];
    const float* Wr1 = (const float*)d_in[1];
    const float* br1 = (const float*)d_in[2];
    const float* Wr2 = (const float*)d_in[3];
    const float* br2 = (const float*)d_in[4];
    const float* Wr3 = (const float*)d_in[5];
    const float* br3 = (const float*)d_in[6];
    const float* Wi1 = (const float*)d_in[7];
    const float* bi1 = (const float*)d_in[8];
    const float* Wi2 = (const float*)d_in[9];
    const float* bi2 = (const float*)d_in[10];
    const float* Wi3 = (const float*)d_in[11];
    const float* bi3 = (const float*)d_in[12];
    const float* Wf1 = (const float*)d_in[13];
    const float* bf1 = (const float*)d_in[14];
    const float* Wf2 = (const float*)d_in[15];
    const float* bf2 = (const float*)d_in[16];
    float* out = (float*)d_out;

    dim3 grid(BP / 256, Fd, 1);
    dim3 block(256, 1, 1);
    hipLaunchKernelGGL(dcp_kernel, grid, block, 0, stream,
                       x, Wr1, br1, Wr2, br2, Wr3, br3,
                       Wi1, bi1, Wi2, bi2, Wi3, bi3,
                       Wf1, bf1, Wf2, bf2, out);
}

// Round 2
// 721.227 us; speedup vs baseline: 1.7577x; 1.7577x over previous
//
#include <hip/hip_runtime.h>
#include <cmath>

namespace {

constexpr int B  = 256;
constexpr int P  = 361;
constexpr int Fd = 20;
constexpr int H1 = 16;
constexpr int H2 = 32;
constexpr int D  = 32;
constexpr int BP = B * P;   // 92416 = 361 * 256 exactly

// Branchless erf approximation (Abramowitz-Stegun 7.1.26), |err| <= 1.5e-7.
// ~14 VALU ops vs ~100 for libm erff (divergent range reduction).
__device__ __forceinline__ float gelu_f(float x) {
    const float u  = x * 0.70710678118654752440f;   // x / sqrt(2)
    const float au = __builtin_fabsf(u);
    const float t  = __builtin_amdgcn_rcpf(__builtin_fmaf(0.3275911f, au, 1.0f));
    float poly = __builtin_fmaf(1.061405429f, t, -1.453152027f);
    poly = __builtin_fmaf(poly, t, 1.421413741f);
    poly = __builtin_fmaf(poly, t, -0.284496736f);
    poly = __builtin_fmaf(poly, t, 0.254829592f);
    poly *= t;
    // exp(-u^2) = exp2(-u^2 * log2(e))
    const float e2 = __builtin_amdgcn_exp2f(-u * u * 1.4426950408889634f);
    const float erf_abs = __builtin_fmaf(-poly, e2, 1.0f);   // erf(|u|)
    const float erf_u = __builtin_copysignf(erf_abs, u);
    return 0.5f * x * (1.0f + erf_u);
}

__device__ __forceinline__ void branch_eval(
    float xv,
    const float* __restrict__ W1, const float* __restrict__ b1,
    const float* __restrict__ W2, const float* __restrict__ b2,
    const float* __restrict__ W3, const float* __restrict__ b3,
    float (&outv)[D])
{
    float h1[H1];
#pragma unroll
    for (int i = 0; i < H1; ++i)
        h1[i] = gelu_f(fmaf(xv, W1[i], b1[i]));

    float h2[H2];
#pragma unroll
    for (int o = 0; o < H2; ++o) {
        float s = b2[o];
#pragma unroll
        for (int i = 0; i < H1; ++i)
            s = fmaf(h1[i], W2[i * H2 + o], s);
        h2[o] = gelu_f(s);
    }

#pragma unroll
    for (int o = 0; o < D; ++o) {
        float s = b3[o];
#pragma unroll
        for (int i = 0; i < H2; ++i)
            s = fmaf(h2[i], W3[i * D + o], s);
        outv[o] = s;
    }
}

__global__ __launch_bounds__(256, 4) void dcp_kernel(
    const float* __restrict__ x,
    const float* __restrict__ Wr1, const float* __restrict__ br1,
    const float* __restrict__ Wr2, const float* __restrict__ br2,
    const float* __restrict__ Wr3, const float* __restrict__ br3,
    const float* __restrict__ Wi1, const float* __restrict__ bi1,
    const float* __restrict__ Wi2, const float* __restrict__ bi2,
    const float* __restrict__ Wi3, const float* __restrict__ bi3,
    const float* __restrict__ Wf1, const float* __restrict__ bf1,
    const float* __restrict__ Wf2, const float* __restrict__ bf2,
    float* __restrict__ out)
{
    const int f  = blockIdx.y;                      // wave-uniform -> scalar weight loads
    const int bp = blockIdx.x * blockDim.x + threadIdx.x;

    const float2 xv = *reinterpret_cast<const float2*>(x + ((size_t)bp * Fd + f) * 2);

    float ro[D], io[D];
    branch_eval(xv.x,
                Wr1 + f * H1, br1 + f * H1,
                Wr2 + f * H1 * H2, br2 + f * H2,
                Wr3 + f * H2 * D, br3 + f * D, ro);
    branch_eval(xv.y,
                Wi1 + f * H1, bi1 + f * H1,
                Wi2 + f * H1 * H2, bi2 + f * H2,
                Wi3 + f * H2 * D, bi3 + f * D, io);

    // fused head layer 1: c = [ro, io] (64) -> 32, gelu
    const float* __restrict__ Wf1f = Wf1 + f * (2 * D) * D;
    const float* __restrict__ bf1f = bf1 + f * D;
    float g[D];
#pragma unroll
    for (int o = 0; o < D; ++o) {
        float s = bf1f[o];
#pragma unroll
        for (int i = 0; i < D; ++i)
            s = fmaf(ro[i], Wf1f[i * D + o], s);
#pragma unroll
        for (int i = 0; i < D; ++i)
            s = fmaf(io[i], Wf1f[(D + i) * D + o], s);
        g[o] = gelu_f(s);
    }

    // fused head layer 2: 32 -> 32, gelu
    const float* __restrict__ Wf2f = Wf2 + f * D * D;
    const float* __restrict__ bf2f = bf2 + f * D;
    float res[D];
#pragma unroll
    for (int o = 0; o < D; ++o) {
        float s = bf2f[o];
#pragma unroll
        for (int i = 0; i < D; ++i)
            s = fmaf(g[i], Wf2f[i * D + o], s);
        res[o] = gelu_f(s);
    }

    float4* __restrict__ outp =
        reinterpret_cast<float4*>(out + ((size_t)bp * Fd + f) * D);
#pragma unroll
    for (int j = 0; j < D / 4; ++j)
        outp[j] = make_float4(res[4 * j], res[4 * j + 1], res[4 * j + 2], res[4 * j + 3]);
}

} // anonymous namespace

extern "C" void kernel_launch(void* const* d_in, const int* in_sizes, int n_in,
                              void* d_out, int out_size, void* d_ws, size_t ws_size,
                              hipStream_t stream)
{
    const float* x   = (const float*)d_in[0];
    const float* Wr1 = (const float*)d_in[1];
    const float* br1 = (const float*)d_in[2];
    const float* Wr2 = (const float*)d_in[3];
    const float* br2 = (const float*)d_in[4];
    const float* Wr3 = (const float*)d_in[5];
    const float* br3 = (const float*)d_in[6];
    const float* Wi1 = (const float*)d_in[7];
    const float* bi1 = (const float*)d_in[8];
    const float* Wi2 = (const float*)d_in[9];
    const float* bi2 = (const float*)d_in[10];
    const float* Wi3 = (const float*)d_in[11];
    const float* bi3 = (const float*)d_in[12];
    const float* Wf1 = (const float*)d_in[13];
    const float* bf1 = (const float*)d_in[14];
    const float* Wf2 = (const float*)d_in[15];
    const float* bf2 = (const float*)d_in[16];
    float* out = (float*)d_out;

    dim3 grid(BP / 256, Fd, 1);
    dim3 block(256, 1, 1);
    hipLaunchKernelGGL(dcp_kernel, grid, block, 0, stream,
                       x, Wr1, br1, Wr2, br2, Wr3, br3,
                       Wi1, bi1, Wi2, bi2, Wi3, bi3,
                       Wf1, bf1, Wf2, bf2, out);
}

// Round 3
// 644.272 us; speedup vs baseline: 1.9677x; 1.1194x over previous
//
#include <hip/hip_runtime.h>

namespace {

constexpr int P   = 361;
constexpr int Fd  = 20;
constexpr int BPc = 256 * P;        // 92416 sites
constexpr int NG  = BPc / 32;       // 2888 site-groups per f
constexpr int GPW = 19;             // groups per wave-stream
constexpr int GX  = (NG / GPW) / 4; // 38 blocks.x (4 waves/block)

typedef __bf16 bf16x8 __attribute__((ext_vector_type(8)));
typedef float  f32x16 __attribute__((ext_vector_type(16)));

__device__ __forceinline__ float gelu_f(float x) {
    const float u  = x * 0.70710678118654752440f;
    const float au = __builtin_fabsf(u);
    const float t  = __builtin_amdgcn_rcpf(__builtin_fmaf(0.3275911f, au, 1.0f));
    float poly = __builtin_fmaf(1.061405429f, t, -1.453152027f);
    poly = __builtin_fmaf(poly, t, 1.421413741f);
    poly = __builtin_fmaf(poly, t, -0.284496736f);
    poly = __builtin_fmaf(poly, t, 0.254829592f);
    poly *= t;
    const float e2 = __builtin_amdgcn_exp2f(-u * u * 1.4426950408889634f);
    const float erf_abs = __builtin_fmaf(-poly, e2, 1.0f);
    const float erf_u = __builtin_copysignf(erf_abs, u);
    return 0.5f * x * (1.0f + erf_u);
}

// round-to-nearest-even bf16 bits
__device__ __forceinline__ unsigned rne_bf16(float v) {
    unsigned b = __builtin_bit_cast(unsigned, v);
    return (b + 0x7FFFu + ((b >> 16) & 1u)) >> 16;
}

// split v ~= hi + lo, both bf16 (16-bit patterns returned in low 16 bits)
__device__ __forceinline__ void split2(float v, unsigned& h, unsigned& l) {
    h = rne_bf16(v);
    l = rne_bf16(v - __builtin_bit_cast(float, h << 16));
}

__device__ __forceinline__ bf16x8 as_bf8(uint4 u) {
    return __builtin_bit_cast(bf16x8, u);
}

// 3-MFMA bf16x3 product: acc += A * B with A = (ah+al) from LDS frags,
// B = (bh+bl) in registers. Drops al*bl (~2^-18 rel).
__device__ __forceinline__ f32x16 mfma3(const uint4* lf, int lane,
                                        uint4 bh, uint4 bl, f32x16 acc) {
    bf16x8 ah = as_bf8(lf[lane]);
    bf16x8 al = as_bf8(lf[64 + lane]);
    acc = __builtin_amdgcn_mfma_f32_32x32x16_bf16(ah, as_bf8(bh), acc, 0, 0, 0);
    acc = __builtin_amdgcn_mfma_f32_32x32x16_bf16(ah, as_bf8(bl), acc, 0, 0, 0);
    acc = __builtin_amdgcn_mfma_f32_32x32x16_bf16(al, as_bf8(bh), acc, 0, 0, 0);
    return acc;
}

// read per-lane bias (accumulator init) from LDS: layout [half*16 + q*4 + e]
// holds bias[row = e + 8q + 4*half], matching C/D row = (r&3)+8*(r>>2)+4*half.
__device__ __forceinline__ f32x16 bias_acc(const float* lb, int half) {
    f32x16 a;
    const float4* p = (const float4*)(lb + half * 16);
#pragma unroll
    for (int q = 0; q < 4; ++q) {
        float4 v = p[q];
        a[4*q+0] = v.x; a[4*q+1] = v.y; a[4*q+2] = v.z; a[4*q+3] = v.w;
    }
    return a;
}

__device__ __forceinline__ void gelu16(f32x16& c) {
#pragma unroll
    for (int e = 0; e < 16; ++e) c[e] = gelu_f(c[e]);
}

// C/D-layout (32 feats x 32 sites) -> two B-fragments (k=0..15, k=16..31),
// hi+lo bf16. C/D: lane holds col n=lane&31, rows (r&3)+8*(r>>2)+4*half.
// B-frag: lane holds n=lane&31, k=(lane>>5)*8+j. Requires a lane^32 half-swap.
__device__ __forceinline__ void transform_cd(const f32x16 c, int lane, int half,
                                             uint4* H, uint4* L) {
    unsigned hd[8], ld[8];
#pragma unroll
    for (int q = 0; q < 4; ++q) {
        unsigned h0, l0, h1, l1, h2, l2, h3, l3;
        split2(c[4*q+0], h0, l0);
        split2(c[4*q+1], h1, l1);
        split2(c[4*q+2], h2, l2);
        split2(c[4*q+3], h3, l3);
        hd[2*q]   = h0 | (h1 << 16);
        hd[2*q+1] = h2 | (h3 << 16);
        ld[2*q]   = l0 | (l1 << 16);
        ld[2*q+1] = l2 | (l3 << 16);
    }
#pragma unroll
    for (int cix = 0; cix < 2; ++cix) {
        const int qlo = 2*cix, qhi = 2*cix + 1;
#pragma unroll
        for (int pr = 0; pr < 2; ++pr) {
            const unsigned* d = pr ? ld : hd;
            unsigned k0 = half ? d[2*qhi]   : d[2*qlo];
            unsigned k1 = half ? d[2*qhi+1] : d[2*qlo+1];
            unsigned s0 = half ? d[2*qlo]   : d[2*qhi];
            unsigned s1 = half ? d[2*qlo+1] : d[2*qhi+1];
            unsigned r0 = (unsigned)__shfl((int)s0, lane ^ 32, 64);
            unsigned r1 = (unsigned)__shfl((int)s1, lane ^ 32, 64);
            uint4 v;
            v.x = half ? r0 : k0;
            v.y = half ? r1 : k1;
            v.z = half ? k0 : r0;
            v.w = half ? k1 : r1;
            (pr ? L : H)[cix] = v;
        }
    }
}

__global__ __launch_bounds__(256, 3) void dcp_mfma_kernel(
    const float* __restrict__ x,
    const float* __restrict__ Wr1, const float* __restrict__ br1,
    const float* __restrict__ Wr2, const float* __restrict__ br2,
    const float* __restrict__ Wr3, const float* __restrict__ br3,
    const float* __restrict__ Wi1, const float* __restrict__ bi1,
    const float* __restrict__ Wi2, const float* __restrict__ bi2,
    const float* __restrict__ Wi3, const float* __restrict__ bi3,
    const float* __restrict__ Wf1, const float* __restrict__ bf1,
    const float* __restrict__ Wf2, const float* __restrict__ bf2,
    float* __restrict__ out)
{
    // 12 weight A-chunks x {hi,lo}: frag fi=2*chunk+prec, per-lane uint4.
    __shared__ uint4 lfrag[24][64];
    __shared__ __align__(16) float lbias[6][32];
    __shared__ float l1w[2][2][16];   // [branch][0=w,1=b][k]

    const int f   = blockIdx.y;
    const int tid = threadIdx.x;

    // ---------- setup: stage weight A-fragments (bf16 hi/lo) into LDS ----------
    // A[m][k] = W[f][k0+k][m]; lane l: m=l&31, k=(l>>5)*8+j.
    for (int s = tid; s < 12 * 64; s += 256) {
        const int chunk = s >> 6;
        const int l     = s & 63;
        const int m     = l & 31;
        const int kb    = (l >> 5) * 8;
        const float* base; int k0;
        switch (chunk) {
            case 0:  base = Wr2 + f * 512;  k0 = 0;  break;
            case 1:  base = Wi2 + f * 512;  k0 = 0;  break;
            case 2:  base = Wr3 + f * 1024; k0 = 0;  break;
            case 3:  base = Wr3 + f * 1024; k0 = 16; break;
            case 4:  base = Wi3 + f * 1024; k0 = 0;  break;
            case 5:  base = Wi3 + f * 1024; k0 = 16; break;
            case 6:  base = Wf1 + f * 2048; k0 = 0;  break;
            case 7:  base = Wf1 + f * 2048; k0 = 16; break;
            case 8:  base = Wf1 + f * 2048; k0 = 32; break;
            case 9:  base = Wf1 + f * 2048; k0 = 48; break;
            case 10: base = Wf2 + f * 1024; k0 = 0;  break;
            default: base = Wf2 + f * 1024; k0 = 16; break;
        }
        unsigned hs[8], ls[8];
#pragma unroll
        for (int j = 0; j < 8; ++j) {
            split2(base[(k0 + kb + j) * 32 + m], hs[j], ls[j]);
        }
        uint4 hv, lv;
        hv.x = hs[0] | (hs[1] << 16); hv.y = hs[2] | (hs[3] << 16);
        hv.z = hs[4] | (hs[5] << 16); hv.w = hs[6] | (hs[7] << 16);
        lv.x = ls[0] | (ls[1] << 16); lv.y = ls[2] | (ls[3] << 16);
        lv.z = ls[4] | (ls[5] << 16); lv.w = ls[6] | (ls[7] << 16);
        lfrag[2 * chunk + 0][l] = hv;
        lfrag[2 * chunk + 1][l] = lv;
    }
    // biases, rearranged to C/D reg order per lane-half
    if (tid < 192) {
        const int set = tid >> 5, i = tid & 31;
        const int row = (i & 3) + 8 * ((i >> 2) & 3) + 4 * (i >> 4);
        const float* bp;
        switch (set) {
            case 0: bp = br2; break; case 1: bp = bi2; break;
            case 2: bp = br3; break; case 3: bp = bi3; break;
            case 4: bp = bf1; break; default: bp = bf2; break;
        }
        lbias[set][i] = bp[f * 32 + row];
    }
    // layer-1 params
    if (tid < 64) {
        const int br = tid >> 5, rem = tid & 31, ty = rem >> 4, k = rem & 15;
        const float* p = br ? (ty ? bi1 : Wi1) : (ty ? br1 : Wr1);
        l1w[br][ty][k] = p[f * 16 + k];
    }
    __syncthreads();

    const int lane    = tid & 63;
    const int wv      = tid >> 6;
    const int n       = lane & 31;
    const int half    = lane >> 5;
    const int kb      = half * 8;
    const int wstream = blockIdx.x * 4 + wv;

    for (int t = 0; t < GPW; ++t) {
        const int g    = wstream * GPW + t;
        const int site = g * 32 + n;
        const float2 xv = *(const float2*)(x + ((size_t)site * Fd + f) * 2);

        // ---- L1 (K=1, on VALU), directly in B-fragment layout ----
        uint4 b1h[2], b1l[2];
#pragma unroll
        for (int br = 0; br < 2; ++br) {
            const float xs = br ? xv.y : xv.x;
            unsigned hs[8], ls[8];
#pragma unroll
            for (int j = 0; j < 8; ++j) {
                float h = gelu_f(fmaf(xs, l1w[br][0][kb + j], l1w[br][1][kb + j]));
                split2(h, hs[j], ls[j]);
            }
            uint4 hv, lv;
            hv.x = hs[0] | (hs[1] << 16); hv.y = hs[2] | (hs[3] << 16);
            hv.z = hs[4] | (hs[5] << 16); hv.w = hs[6] | (hs[7] << 16);
            lv.x = ls[0] | (ls[1] << 16); lv.y = ls[2] | (ls[3] << 16);
            lv.z = ls[4] | (ls[5] << 16); lv.w = ls[6] | (ls[7] << 16);
            b1h[br] = hv; b1l[br] = lv;
        }

        // ---- L2: 16 -> 32, gelu ----
        f32x16 cr = bias_acc(lbias[0], half);
        f32x16 ci = bias_acc(lbias[1], half);
        cr = mfma3(&lfrag[0][0], lane, b1h[0], b1l[0], cr);
        ci = mfma3(&lfrag[2][0], lane, b1h[1], b1l[1], ci);
        gelu16(cr); gelu16(ci);
        uint4 b2h[2][2], b2l[2][2];
        transform_cd(cr, lane, half, b2h[0], b2l[0]);
        transform_cd(ci, lane, half, b2h[1], b2l[1]);

        // ---- L3: 32 -> 32, linear ----
        f32x16 ro = bias_acc(lbias[2], half);
        f32x16 io = bias_acc(lbias[3], half);
        ro = mfma3(&lfrag[4][0],  lane, b2h[0][0], b2l[0][0], ro);
        ro = mfma3(&lfrag[6][0],  lane, b2h[0][1], b2l[0][1], ro);
        io = mfma3(&lfrag[8][0],  lane, b2h[1][0], b2l[1][0], io);
        io = mfma3(&lfrag[10][0], lane, b2h[1][1], b2l[1][1], io);
        uint4 fh[4], fl[4];
        transform_cd(ro, lane, half, &fh[0], &fl[0]);   // F1 k = 0..31
        transform_cd(io, lane, half, &fh[2], &fl[2]);   // F1 k = 32..63

        // ---- F1: 64 -> 32, gelu ----
        f32x16 c1 = bias_acc(lbias[4], half);
        c1 = mfma3(&lfrag[12][0], lane, fh[0], fl[0], c1);
        c1 = mfma3(&lfrag[14][0], lane, fh[1], fl[1], c1);
        c1 = mfma3(&lfrag[16][0], lane, fh[2], fl[2], c1);
        c1 = mfma3(&lfrag[18][0], lane, fh[3], fl[3], c1);
        gelu16(c1);
        uint4 gh[2], gl[2];
        transform_cd(c1, lane, half, gh, gl);

        // ---- F2: 32 -> 32, gelu ----
        f32x16 c2 = bias_acc(lbias[5], half);
        c2 = mfma3(&lfrag[20][0], lane, gh[0], gl[0], c2);
        c2 = mfma3(&lfrag[22][0], lane, gh[1], gl[1], c2);
        gelu16(c2);

        // ---- store: lane covers feats {4*half + 8q + e} of its site ----
        float* op = out + ((size_t)site * Fd + f) * 32 + 4 * half;
#pragma unroll
        for (int q = 0; q < 4; ++q) {
            *(float4*)(op + q * 8) =
                make_float4(c2[4*q+0], c2[4*q+1], c2[4*q+2], c2[4*q+3]);
        }
    }
}

} // anonymous namespace

extern "C" void kernel_launch(void* const* d_in, const int* in_sizes, int n_in,
                              void* d_out, int out_size, void* d_ws, size_t ws_size,
                              hipStream_t stream)
{
    const float* x   = (const float*)d_in[0];
    const float* Wr1 = (const float*)d_in[1];
    const float* br1 = (const float*)d_in[2];
    const float* Wr2 = (const float*)d_in[3];
    const float* br2 = (const float*)d_in[4];
    const float* Wr3 = (const float*)d_in[5];
    const float* br3 = (const float*)d_in[6];
    const float* Wi1 = (const float*)d_in[7];
    const float* bi1 = (const float*)d_in[8];
    const float* Wi2 = (const float*)d_in[9];
    const float* bi2 = (const float*)d_in[10];
    const float* Wi3 = (const float*)d_in[11];
    const float* bi3 = (const float*)d_in[12];
    const float* Wf1 = (const float*)d_in[13];
    const float* bf1 = (const float*)d_in[14];
    const float* Wf2 = (const float*)d_in[15];
    const float* bf2 = (const float*)d_in[16];
    float* out = (float*)d_out;

    dim3 grid(GX, Fd, 1);
    dim3 block(256, 1, 1);
    hipLaunchKernelGGL(dcp_mfma_kernel, grid, block, 0, stream,
                       x, Wr1, br1, Wr2, br2, Wr3, br3,
                       Wi1, bi1, Wi2, bi2, Wi3, bi3,
                       Wf1, bf1, Wf2, bf2, out);
}